// Round 1
// 166.391 us; speedup vs baseline: 1.0741x; 1.0741x over previous
//
#include <hip/hip_runtime.h>
#include <hip/hip_bf16.h>

#define N_NODES 50000
#define N_EDGES 800000
#define KPTS 15
#define IN_DIM 32
#define OUT_DIM 64
#define KP_EXTENT 0.6f

#define CAP 131072          // per-k list capacity (expected ~13k/k, 10x margin)
#define CNT_STRIDE 64       // ints: 256B between counters -> distinct L2 channels
#define K1_BLOCKS (N_EDGES / 256)   // 800000/256 = 3125 exactly
#define BPK 256             // blocks per kernel-point in K2 (was 64 -> 4x TLP)

// ws layout: [0, 4096) padded counters; [4096, ...) 15 lists of CAP uint2
#define LIST_OFF 4096

// ---------------------------------------------------------------------------
// K1: geometry (1 lane = 1 edge) + ballot compaction into per-k pair lists.
// Also zeroes `out`: 800000 threads x float4 == 50000*64 floats exactly,
// replacing the separate 12.8 MB hipMemsetAsync dispatch.
// ---------------------------------------------------------------------------
__global__ __launch_bounds__(256) void geom_compact(
    const float* __restrict__ pos,
    const float* __restrict__ kp,
    const int*   __restrict__ esrc,
    const int*   __restrict__ edst,
    int*         __restrict__ cnt,     // padded counters
    uint2*       __restrict__ lists,   // 15 * CAP entries
    float4*      __restrict__ outz)    // out viewed as float4[800000]
{
    __shared__ int s_wavecnt[KPTS][4];
    __shared__ int s_woff[KPTS][4];
    __shared__ int s_base[KPTS];

    const int tid  = threadIdx.x;
    const int wv   = tid >> 6;
    const int lane = tid & 63;

    const int e = blockIdx.x * 256 + tid;      // grid covers E exactly

    // zero the output (fire-and-forget store, overlaps with the compute below)
    outz[e] = make_float4(0.0f, 0.0f, 0.0f, 0.0f);

    const int s = esrc[e];
    const int d = edst[e];

    const float yx = pos[s * 3 + 0] - pos[d * 3 + 0];
    const float yy = pos[s * 3 + 1] - pos[d * 3 + 1];
    const float yz = pos[s * 3 + 2] - pos[d * 3 + 2];

    float m[KPTS];
    unsigned act = 0;
    #pragma unroll
    for (int k = 0; k < KPTS; ++k) {
        const float dx = yx - kp[k * 3 + 0];
        const float dy = yy - kp[k * 3 + 1];
        const float dz = yz - kp[k * 3 + 2];
        const float dist = sqrtf(dx * dx + dy * dy + dz * dz);
        const float mk = 1.0f - dist * (1.0f / KP_EXTENT);
        m[k] = mk;
        if (mk > 0.0f) act |= (1u << k);
    }

    // per-wave popcounts
    #pragma unroll
    for (int k = 0; k < KPTS; ++k) {
        const unsigned long long mask = __ballot((act >> k) & 1u);
        if (lane == 0) s_wavecnt[k][wv] = __popcll(mask);
    }
    __syncthreads();

    if (tid < KPTS) {
        int o0 = 0;
        int total = 0;
        #pragma unroll
        for (int w = 0; w < 4; ++w) {
            s_woff[tid][w] = o0;
            o0 += s_wavecnt[tid][w];
        }
        total = o0;
        s_base[tid] = (total > 0) ? atomicAdd(&cnt[tid * CNT_STRIDE], total) : 0;
    }
    __syncthreads();

    const unsigned long long lt = (lane == 63) ? 0x7fffffffffffffffull
                                               : ((1ull << lane) - 1ull);
    const unsigned sd = ((unsigned)s << 16) | (unsigned)d;
    #pragma unroll
    for (int k = 0; k < KPTS; ++k) {
        const bool a = (act >> k) & 1u;
        const unsigned long long mask = __ballot(a);
        if (a) {
            const int rank = __popcll(mask & lt);
            const int idx  = s_base[k] + s_woff[k][wv] + rank;
            if (idx < CAP)
                lists[(size_t)k * CAP + idx] = make_uint2(sd, __float_as_uint(m[k]));
        }
    }
}

// ---------------------------------------------------------------------------
// K2: one wave per 2-pair chunk; lane = output channel. W[k] column held in
// 32 VGPRs per lane; feat rows arrive as uniform (scalar) loads.
// 2 pairs/iter x 2 half-dot accumulators = 4 independent FMA chains (ILP),
// single dwordx4 broadcast load fetches both list entries.
// ---------------------------------------------------------------------------
__global__ __launch_bounds__(256) void pair_matmul(
    const float* __restrict__ feat,
    const float* __restrict__ W,       // [15][32][64]
    const int*   __restrict__ cnt,
    const uint2* __restrict__ lists,
    float*       __restrict__ out)
{
    const int k    = blockIdx.x % KPTS;
    const int bk   = blockIdx.x / KPTS;          // 0..BPK-1
    const int wv   = threadIdx.x >> 6;
    const int lane = threadIdx.x & 63;

    // preload W[k][i][lane], i = 0..31  -> 32 VGPRs
    float w[IN_DIM];
    #pragma unroll
    for (int i = 0; i < IN_DIM; ++i)
        w[i] = W[k * (IN_DIM * OUT_DIM) + i * OUT_DIM + lane];

    int n = cnt[k * CNT_STRIDE];
    if (n > CAP) n = CAP;
    const uint2* __restrict__ list = lists + (size_t)k * CAP;

    const int widx    = bk * 4 + wv;             // 0..BPK*4-1
    const int stride2 = BPK * 4 * 2;             // pair step between chunks

    for (int base = widx * 2; base < n; base += stride2) {
        if (base + 1 < n) {
            // 16B-aligned (base even), broadcast across the wave
            const uint4 ee = *reinterpret_cast<const uint4*>(list + base);
            const unsigned sd0 = (unsigned)__builtin_amdgcn_readfirstlane((int)ee.x);
            const float    m0  = __uint_as_float(ee.y);
            const unsigned sd1 = (unsigned)__builtin_amdgcn_readfirstlane((int)ee.z);
            const float    m1  = __uint_as_float(ee.w);

            const float* __restrict__ f0 = feat + ((sd0 >> 16) << 5);  // uniform -> s_load
            const float* __restrict__ f1 = feat + ((sd1 >> 16) << 5);

            float a0 = 0.0f, b0 = 0.0f, a1 = 0.0f, b1 = 0.0f;
            #pragma unroll
            for (int i = 0; i < 16; ++i) {
                a0 = fmaf(f0[i],      w[i],      a0);
                b0 = fmaf(f0[i + 16], w[i + 16], b0);
                a1 = fmaf(f1[i],      w[i],      a1);
                b1 = fmaf(f1[i + 16], w[i + 16], b1);
            }
            atomicAdd(out + (size_t)(sd0 & 0xffffu) * OUT_DIM + lane, m0 * (a0 + b0));
            atomicAdd(out + (size_t)(sd1 & 0xffffu) * OUT_DIM + lane, m1 * (a1 + b1));
        } else {
            const uint2 ent = list[base];
            const unsigned sd = (unsigned)__builtin_amdgcn_readfirstlane((int)ent.x);
            const float    m  = __uint_as_float(ent.y);
            const float* __restrict__ f = feat + ((sd >> 16) << 5);

            float a = 0.0f, b = 0.0f;
            #pragma unroll
            for (int i = 0; i < 16; ++i) {
                a = fmaf(f[i],      w[i],      a);
                b = fmaf(f[i + 16], w[i + 16], b);
            }
            atomicAdd(out + (size_t)(sd & 0xffffu) * OUT_DIM + lane, m * (a + b));
        }
    }
}

// ---------------------------------------------------------------------------
extern "C" void kernel_launch(void* const* d_in, const int* in_sizes, int n_in,
                              void* d_out, int out_size, void* d_ws, size_t ws_size,
                              hipStream_t stream)
{
    const float* pos  = (const float*)d_in[0];   // [50000,3]
    const float* feat = (const float*)d_in[1];   // [50000,32]
    const float* kp   = (const float*)d_in[2];   // [15,3]
    const float* W    = (const float*)d_in[3];   // [15,32,64]
    const int* esrc   = (const int*)d_in[4];     // [800000]
    const int* edst   = (const int*)d_in[5];     // [800000]
    float* out        = (float*)d_out;           // [50000,64]

    int*   cnt   = (int*)d_ws;
    uint2* lists = (uint2*)((char*)d_ws + LIST_OFF);

    hipMemsetAsync(cnt, 0, LIST_OFF, stream);   // 4 KB counters only

    geom_compact<<<K1_BLOCKS, 256, 0, stream>>>(pos, kp, esrc, edst, cnt, lists,
                                                (float4*)out);
    pair_matmul<<<BPK * KPTS, 256, 0, stream>>>(feat, W, cnt, lists, out);
}